// Round 7
// baseline (660.792 us; speedup 1.0000x reference)
//
#include <hip/hip_runtime.h>
#include <hip/hip_bf16.h>

typedef unsigned int u32;
typedef unsigned short u16;

__device__ __forceinline__ u16 f2bf(float f){ u32 x; __builtin_memcpy(&x,&f,4); u32 r=(x+0x7fffu+((x>>16)&1u))>>16; return (u16)r; }
__device__ __forceinline__ float lo2f(u32 u){ u32 x=u<<16; float f; __builtin_memcpy(&f,&x,4); return f; }
__device__ __forceinline__ float hi2f(u32 u){ u32 x=u&0xffff0000u; float f; __builtin_memcpy(&f,&x,4); return f; }

// ---------------- K1/K3: split-K GEMM: (32 x K f32) @ (K x N f32) -> partials ----------------
// grid: (N/256, splits), block 256. One column per thread.
__global__ __launch_bounds__(256) void gemm_splitk(
    const float* __restrict__ A, const float* __restrict__ W,
    float* __restrict__ P, int K, int N, int dps)
{
    const int j = blockIdx.x*256 + threadIdx.x;
    const int s = blockIdx.y;
    float acc[32];
    #pragma unroll
    for (int b=0;b<32;++b) acc[b]=0.f;
    const int d0 = s*dps, d1 = d0+dps;
    #pragma unroll 4
    for (int d=d0; d<d1; ++d) {
        const float wv = W[(size_t)d*N + j];
        #pragma unroll
        for (int b=0;b<32;++b)
            acc[b] = fmaf(A[b*K + d], wv, acc[b]);
    }
    float* Pp = P + (size_t)(s*32)*N + j;
    #pragma unroll
    for (int b=0;b<32;++b) Pp[(size_t)b*N] = acc[b];
}

// ---------------- K2: reduce partials + RoPE + pack q/k/v ----------------
__global__ __launch_bounds__(256) void qkv_finish(
    const float* __restrict__ P, const float* __restrict__ cosc,
    const float* __restrict__ sinc, const int* __restrict__ spp,
    float* __restrict__ qws, float* __restrict__ kn, float* __restrict__ vn,
    int splits)
{
    const int col = blockIdx.x*256 + threadIdx.x;
    const int b = blockIdx.y;
    float v = 0.f;
    for (int s=0;s<splits;++s) v += P[(size_t)(s*32+b)*6144 + col];
    if (col < 5120) {
        const int d = col & 127;
        const int partner = (col & ~127) | ((d<64)? d+64 : d-64);
        float pv = 0.f;
        for (int s=0;s<splits;++s) pv += P[(size_t)(s*32+b)*6144 + partner];
        const int spos = *spp;
        const float c  = cosc[spos*128 + d];
        const float sn = sinc[spos*128 + d];
        const float rot = (d<64)? -pv : pv;
        const float val = fmaf(v, c, rot*sn);
        if (col < 4096) qws[(size_t)b*4096 + col] = val;
        else            kn[(size_t)b*1024 + (col-4096)] = val;
    } else {
        vn[(size_t)b*1024 + (col-5120)] = v;
    }
}

// ---------------- K4: fused attention, 1024 threads = 16 waves per (b,kv) block ----------------
__global__ __launch_bounds__(1024, 4) void attn_kernel(
    const float* __restrict__ qws, const float* __restrict__ Kc,
    const float* __restrict__ Vc, const float* __restrict__ kn,
    const float* __restrict__ vn, const float* __restrict__ mask,
    const int* __restrict__ curp, float* __restrict__ aout,
    const int PL, const int SW)
{
    __shared__ uint2 probsP[4096];        // 32 KB: 4 bf16 probs per position
    __shared__ float obuf[16][4][128];    // 32 KB: [wave][head][d]
    __shared__ float redm[16][4];
    __shared__ float reds[16][4];

    const int t = threadIdx.x;
    const int lane = t & 63;
    const int w = t >> 6;
    const int b  = blockIdx.x >> 3;
    const int kv = blockIdx.x & 7;
    const int cur = *curp;

    const size_t mat = (size_t)(b*8+kv);
    const float* __restrict__ Kb  = Kc + mat*(size_t)SW*128;
    const float* __restrict__ knr = kn + mat*128;
    const float* __restrict__ qbase = qws + (size_t)(b*32 + kv*4)*128;

    // ---- Phase A: scores. Thread covers p = i*1024 + t, i=0..3; row streamed dc-inner. ----
    float s[4][4];   // [head][i]
    #pragma unroll
    for (int i=0;i<4;++i) {
        const int p = i*1024 + t;
        float acc0=0.f, acc1=0.f, acc2=0.f, acc3=0.f;
        if (p < PL) {
            const float* __restrict__ row = (p==cur) ? knr : (Kb + (size_t)p*128);
            #pragma unroll
            for (int dc=0; dc<16; ++dc) {
                const float4 ka = *reinterpret_cast<const float4*>(row + dc*8);
                const float4 kb = *reinterpret_cast<const float4*>(row + dc*8 + 4);
                const float* __restrict__ q0 = qbase + dc*8;
                #pragma unroll
                for (int j=0;j<4;++j) {
                    const float kj = (j==0)?ka.x:(j==1)?ka.y:(j==2)?ka.z:ka.w;
                    acc0 = fmaf(q0[j      ], kj, acc0);
                    acc1 = fmaf(q0[j+128  ], kj, acc1);
                    acc2 = fmaf(q0[j+256  ], kj, acc2);
                    acc3 = fmaf(q0[j+384  ], kj, acc3);
                }
                #pragma unroll
                for (int j=0;j<4;++j) {
                    const float kj = (j==0)?kb.x:(j==1)?kb.y:(j==2)?kb.z:kb.w;
                    acc0 = fmaf(q0[j+4    ], kj, acc0);
                    acc1 = fmaf(q0[j+132  ], kj, acc1);
                    acc2 = fmaf(q0[j+260  ], kj, acc2);
                    acc3 = fmaf(q0[j+388  ], kj, acc3);
                }
            }
        }
        s[0][i]=acc0; s[1][i]=acc1; s[2][i]=acc2; s[3][i]=acc3;
    }

    // ---- scale + mask (+ invalidate tail) ----
    const float scale = 0.08838834764831845f; // 1/sqrt(128)
    const size_t mbase = ((size_t)b*32 + (size_t)kv*4)*(size_t)PL;
    #pragma unroll
    for (int i=0;i<4;++i) {
        const int p = i*1024 + t;
        if (p < PL) {
            #pragma unroll
            for (int h=0;h<4;++h) {
                const float mv = mask[mbase + (size_t)h*PL + p];
                s[h][i] = fmaf(s[h][i], scale, mv);
            }
        } else {
            #pragma unroll
            for (int h=0;h<4;++h) s[h][i] = -3.0e38f;
        }
    }

    // ---- softmax: block max over 16 waves ----
    float lm[4];
    #pragma unroll
    for (int h=0;h<4;++h) {
        lm[h] = fmaxf(fmaxf(s[h][0],s[h][1]), fmaxf(s[h][2],s[h][3]));
    }
    #pragma unroll
    for (int off=1; off<64; off<<=1) {
        #pragma unroll
        for (int h=0;h<4;++h) lm[h] = fmaxf(lm[h], __shfl_xor(lm[h], off, 64));
    }
    if (lane==0) {
        #pragma unroll
        for (int h=0;h<4;++h) redm[w][h] = lm[h];
    }
    __syncthreads();
    float M[4];
    #pragma unroll
    for (int h=0;h<4;++h) {
        float m = redm[0][h];
        #pragma unroll
        for (int ww=1;ww<16;++ww) m = fmaxf(m, redm[ww][h]);
        M[h] = m;
    }

    // ---- exp + block sum ----
    float ls[4] = {0.f,0.f,0.f,0.f};
    #pragma unroll
    for (int i=0;i<4;++i) {
        #pragma unroll
        for (int h=0;h<4;++h) {
            const float e = __expf(s[h][i] - M[h]);
            s[h][i] = e;
            ls[h] += e;
        }
    }
    #pragma unroll
    for (int off=1; off<64; off<<=1) {
        #pragma unroll
        for (int h=0;h<4;++h) ls[h] += __shfl_xor(ls[h], off, 64);
    }
    if (lane==0) {
        #pragma unroll
        for (int h=0;h<4;++h) reds[w][h] = ls[h];
    }
    __syncthreads();
    float inv[4];
    #pragma unroll
    for (int h=0;h<4;++h) {
        float sm = reds[0][h];
        #pragma unroll
        for (int ww=1;ww<16;++ww) sm += reds[ww][h];
        inv[h] = 1.f / sm;
    }

    // ---- write normalized probs (bf16 packed) ----
    #pragma unroll
    for (int i=0;i<4;++i) {
        const int p = i*1024 + t;
        if (p < PL) {
            const u32 plo = (u32)f2bf(s[0][i]*inv[0]) | ((u32)f2bf(s[1][i]*inv[1]) << 16);
            const u32 phi = (u32)f2bf(s[2][i]*inv[2]) | ((u32)f2bf(s[3][i]*inv[3]) << 16);
            probsP[p] = make_uint2(plo, phi);
        }
    }
    __syncthreads();

    // ---- Phase PV: wave w covers positions [w*PL/16, (w+1)*PL/16), lane covers d=2*lane,2*lane+1 ----
    const float* __restrict__ Vb  = Vc + mat*(size_t)SW*128;
    const float* __restrict__ vnr = vn + mat*128;
    const int chunk = PL >> 4;
    const int p0 = w*chunk, p1 = p0 + chunk;
    float a0[4] = {0.f,0.f,0.f,0.f}, a1[4] = {0.f,0.f,0.f,0.f};
    #pragma unroll 8
    for (int p=p0; p<p1; ++p) {
        const float* row = (p==cur) ? vnr : (Vb + (size_t)p*128);
        const float2 vv = *reinterpret_cast<const float2*>(row + 2*lane);
        const uint2 pp = probsP[p];
        const float pr0 = lo2f(pp.x), pr1 = hi2f(pp.x);
        const float pr2 = lo2f(pp.y), pr3 = hi2f(pp.y);
        a0[0]=fmaf(pr0,vv.x,a0[0]); a1[0]=fmaf(pr0,vv.y,a1[0]);
        a0[1]=fmaf(pr1,vv.x,a0[1]); a1[1]=fmaf(pr1,vv.y,a1[1]);
        a0[2]=fmaf(pr2,vv.x,a0[2]); a1[2]=fmaf(pr2,vv.y,a1[2]);
        a0[3]=fmaf(pr3,vv.x,a0[3]); a1[3]=fmaf(pr3,vv.y,a1[3]);
    }
    #pragma unroll
    for (int h=0;h<4;++h)
        *reinterpret_cast<float2*>(&obuf[w][h][2*lane]) = make_float2(a0[h], a1[h]);
    __syncthreads();

    // ---- cross-wave reduce + writeout ----
    if (t < 512) {
        const int h = t >> 7;
        const int d = t & 127;
        float sum = obuf[0][h][d];
        #pragma unroll
        for (int ww=1;ww<16;++ww) sum += obuf[ww][h][d];
        aout[(size_t)(b*32 + kv*4 + h)*128 + d] = sum;
    }
}

// ---------------- K5: reduce wo partials -> f32 output ----------------
__global__ __launch_bounds__(256) void wo_finish(
    const float* __restrict__ P, float* __restrict__ out, int splits)
{
    const int col = blockIdx.x*256 + threadIdx.x;
    const int b = blockIdx.y;
    float v = 0.f;
    for (int s=0;s<splits;++s) v += P[(size_t)(s*32+b)*4096 + col];
    out[(size_t)b*4096 + col] = v;
}

extern "C" void kernel_launch(void* const* d_in, const int* in_sizes, int n_in,
                              void* d_out, int out_size, void* d_ws, size_t ws_size,
                              hipStream_t stream)
{
    const float* x    = (const float*)d_in[0];
    const float* wqkv = (const float*)d_in[1];
    const float* wo   = (const float*)d_in[2];
    const float* cK   = (const float*)d_in[3];
    const float* cV   = (const float*)d_in[4];
    const float* cosc = (const float*)d_in[5];
    const float* sinc = (const float*)d_in[6];
    const float* mask = (const float*)d_in[7];
    const int* sp   = (const int*)d_in[8];
    const int* cp   = (const int*)d_in[9];

    const int PL = in_sizes[7] / (32*32);          // padded_len (4032)
    const int SW = in_sizes[3] / (32*8*128);       // cache rows (4096)

    char* ws = (char*)d_ws;
    float* qws  = (float*)(ws);                          // 512 KB
    float* aout = (float*)(ws + 524288);                 // 512 KB
    float* kn   = (float*)(ws + 2*524288);               // 128 KB
    float* vn   = (float*)(ws + 2*524288 + 131072);      // 128 KB
    float* Pbuf = (float*)(ws + 2*524288 + 2*131072);    // split-K partials

    int splits = 32;
    {
        const size_t fixed = 2ull*524288 + 2ull*131072;
        while (splits > 4 && fixed + (size_t)splits*32*6144*4 > ws_size) splits >>= 1;
    }
    const int dps = 4096 / splits;

    // ===== DUPLICATION PROBE: every non-attn kernel launched twice (idempotent).
    // dur_us - 455 == true warm cost of the gemm/finish chain.
    gemm_splitk<<<dim3(24, splits), 256, 0, stream>>>(x, wqkv, Pbuf, 4096, 6144, dps);
    gemm_splitk<<<dim3(24, splits), 256, 0, stream>>>(x, wqkv, Pbuf, 4096, 6144, dps);
    qkv_finish<<<dim3(24, 32), 256, 0, stream>>>(Pbuf, cosc, sinc, sp, qws, kn, vn, splits);
    qkv_finish<<<dim3(24, 32), 256, 0, stream>>>(Pbuf, cosc, sinc, sp, qws, kn, vn, splits);

    attn_kernel<<<256, 1024, 0, stream>>>(qws, cK, cV, kn, vn, mask, cp, aout, PL, SW);

    gemm_splitk<<<dim3(16, splits), 256, 0, stream>>>(aout, wo, Pbuf, 4096, 4096, dps);
    gemm_splitk<<<dim3(16, splits), 256, 0, stream>>>(aout, wo, Pbuf, 4096, 4096, dps);
    wo_finish<<<dim3(16, 32), 256, 0, stream>>>(Pbuf, (float*)d_out, splits);
    wo_finish<<<dim3(16, 32), 256, 0, stream>>>(Pbuf, (float*)d_out, splits);
}

// Round 8
// 338.720 us; speedup vs baseline: 1.9508x; 1.9508x over previous
//
#include <hip/hip_runtime.h>
#include <hip/hip_bf16.h>

typedef unsigned int u32;
typedef unsigned short u16;

__device__ __forceinline__ u16 f2bf(float f){ u32 x; __builtin_memcpy(&x,&f,4); u32 r=(x+0x7fffu+((x>>16)&1u))>>16; return (u16)r; }
__device__ __forceinline__ float lo2f(u32 u){ u32 x=u<<16; float f; __builtin_memcpy(&f,&x,4); return f; }
__device__ __forceinline__ float hi2f(u32 u){ u32 x=u&0xffff0000u; float f; __builtin_memcpy(&f,&x,4); return f; }

// ---------------- K0: transpose x (32 x 4096) -> xt (4096 x 32) ----------------
// block: 256 thr handles a 64(d) x 32(b) tile. grid 64.
__global__ __launch_bounds__(256) void transpose_x(
    const float* __restrict__ x, float* __restrict__ xt)
{
    __shared__ float ld[32][65];
    const int t = threadIdx.x;
    const int g = blockIdx.x;
    #pragma unroll
    for (int i=0;i<8;++i) {
        const int e = i*256 + t;
        const int b = e >> 6, dd = e & 63;
        ld[b][dd] = x[(size_t)b*4096 + g*64 + dd];
    }
    __syncthreads();
    #pragma unroll
    for (int i=0;i<8;++i) {
        const int e = i*256 + t;
        const int dd = e >> 5, b = e & 31;
        xt[(size_t)(g*64 + dd)*32 + b] = ld[b][dd];
    }
}

// ---------------- K1/K3: split-K GEMM with transposed A: (K x 32) ----------------
// grid: (N/512, splits), block 256. Thread covers float2 column j2.
__global__ __launch_bounds__(256) void gemm_splitk_t(
    const float* __restrict__ At, const float2* __restrict__ W2,
    float* __restrict__ P, int K, int N, int dps)
{
    const int j2 = blockIdx.x*256 + threadIdx.x;
    const int s = blockIdx.y;
    float acc0[32], acc1[32];
    #pragma unroll
    for (int b=0;b<32;++b){ acc0[b]=0.f; acc1[b]=0.f; }
    const int d0 = s*dps, d1 = d0 + dps;
    const int halfN = N >> 1;
    #pragma unroll 2
    for (int d=d0; d<d1; ++d) {
        const float2 wv = W2[(size_t)d*halfN + j2];
        const float* __restrict__ Ad = At + d*32;   // contiguous 128B, wave-uniform -> s_load
        #pragma unroll
        for (int b=0;b<32;++b) {
            const float av = Ad[b];
            acc0[b] = fmaf(av, wv.x, acc0[b]);
            acc1[b] = fmaf(av, wv.y, acc1[b]);
        }
    }
    float* Pp = P + (size_t)(s*32)*N + 2*j2;
    #pragma unroll
    for (int b=0;b<32;++b)
        *reinterpret_cast<float2*>(Pp + (size_t)b*N) = make_float2(acc0[b], acc1[b]);
}

// ---------------- K2: reduce partials + RoPE + pack q/k/v (partner via LDS) ----------------
__global__ __launch_bounds__(256) void qkv_finish(
    const float* __restrict__ P, const float* __restrict__ cosc,
    const float* __restrict__ sinc, const int* __restrict__ spp,
    float* __restrict__ qws, float* __restrict__ kn, float* __restrict__ vn,
    int splits)
{
    __shared__ float sh[256];
    const int t = threadIdx.x;
    const int col = blockIdx.x*256 + t;
    const int b = blockIdx.y;
    float v = 0.f;
    for (int s=0;s<splits;++s) v += P[(size_t)(s*32+b)*6144 + col];
    sh[t] = v;
    __syncthreads();
    if (col < 5120) {
        const int d = col & 127;
        const int pt = (t & ~127) | ((d<64)? d+64 : d-64);
        const float pv = sh[pt];
        const int spos = *spp;
        const float c  = cosc[spos*128 + d];
        const float sn = sinc[spos*128 + d];
        const float rot = (d<64)? -pv : pv;
        const float val = fmaf(v, c, rot*sn);
        if (col < 4096) qws[(size_t)b*4096 + col] = val;
        else            kn[(size_t)b*1024 + (col-4096)] = val;
    } else {
        vn[(size_t)b*1024 + (col-5120)] = v;
    }
}

// ---------------- K4: fused attention, 1024 threads = 16 waves per (b,kv) block ----------------
__global__ __launch_bounds__(1024, 4) void attn_kernel(
    const float* __restrict__ qws, const float* __restrict__ Kc,
    const float* __restrict__ Vc, const float* __restrict__ kn,
    const float* __restrict__ vn, const float* __restrict__ mask,
    const int* __restrict__ curp, float* __restrict__ aout_t,
    const int PL, const int SW)
{
    __shared__ uint2 probsP[4096];        // 32 KB: 4 bf16 probs per position
    __shared__ float obuf[16][4][128];    // 32 KB: [wave][head][d]
    __shared__ float redm[16][4];
    __shared__ float reds[16][4];

    const int t = threadIdx.x;
    const int lane = t & 63;
    const int w = t >> 6;
    const int b  = blockIdx.x >> 3;
    const int kv = blockIdx.x & 7;
    const int cur = *curp;

    const size_t mat = (size_t)(b*8+kv);
    const float* __restrict__ Kb  = Kc + mat*(size_t)SW*128;
    const float* __restrict__ knr = kn + mat*128;
    const float* __restrict__ qbase = qws + (size_t)(b*32 + kv*4)*128;

    // ---- Phase A: scores. Thread covers p = i*1024 + t, i=0..3; row streamed dc-inner. ----
    float s[4][4];   // [head][i]
    #pragma unroll
    for (int i=0;i<4;++i) {
        const int p = i*1024 + t;
        float acc0=0.f, acc1=0.f, acc2=0.f, acc3=0.f;
        if (p < PL) {
            const float* __restrict__ row = (p==cur) ? knr : (Kb + (size_t)p*128);
            #pragma unroll
            for (int dc=0; dc<16; ++dc) {
                const float4 ka = *reinterpret_cast<const float4*>(row + dc*8);
                const float4 kb = *reinterpret_cast<const float4*>(row + dc*8 + 4);
                const float* __restrict__ q0 = qbase + dc*8;
                #pragma unroll
                for (int j=0;j<4;++j) {
                    const float kj = (j==0)?ka.x:(j==1)?ka.y:(j==2)?ka.z:ka.w;
                    acc0 = fmaf(q0[j      ], kj, acc0);
                    acc1 = fmaf(q0[j+128  ], kj, acc1);
                    acc2 = fmaf(q0[j+256  ], kj, acc2);
                    acc3 = fmaf(q0[j+384  ], kj, acc3);
                }
                #pragma unroll
                for (int j=0;j<4;++j) {
                    const float kj = (j==0)?kb.x:(j==1)?kb.y:(j==2)?kb.z:kb.w;
                    acc0 = fmaf(q0[j+4    ], kj, acc0);
                    acc1 = fmaf(q0[j+132  ], kj, acc1);
                    acc2 = fmaf(q0[j+260  ], kj, acc2);
                    acc3 = fmaf(q0[j+388  ], kj, acc3);
                }
            }
        }
        s[0][i]=acc0; s[1][i]=acc1; s[2][i]=acc2; s[3][i]=acc3;
    }

    // ---- scale + mask (+ invalidate tail) ----
    const float scale = 0.08838834764831845f; // 1/sqrt(128)
    const size_t mbase = ((size_t)b*32 + (size_t)kv*4)*(size_t)PL;
    #pragma unroll
    for (int i=0;i<4;++i) {
        const int p = i*1024 + t;
        if (p < PL) {
            #pragma unroll
            for (int h=0;h<4;++h) {
                const float mv = mask[mbase + (size_t)h*PL + p];
                s[h][i] = fmaf(s[h][i], scale, mv);
            }
        } else {
            #pragma unroll
            for (int h=0;h<4;++h) s[h][i] = -3.0e38f;
        }
    }

    // ---- softmax: block max over 16 waves ----
    float lm[4];
    #pragma unroll
    for (int h=0;h<4;++h) {
        lm[h] = fmaxf(fmaxf(s[h][0],s[h][1]), fmaxf(s[h][2],s[h][3]));
    }
    #pragma unroll
    for (int off=1; off<64; off<<=1) {
        #pragma unroll
        for (int h=0;h<4;++h) lm[h] = fmaxf(lm[h], __shfl_xor(lm[h], off, 64));
    }
    if (lane==0) {
        #pragma unroll
        for (int h=0;h<4;++h) redm[w][h] = lm[h];
    }
    __syncthreads();
    float M[4];
    #pragma unroll
    for (int h=0;h<4;++h) {
        float m = redm[0][h];
        #pragma unroll
        for (int ww=1;ww<16;++ww) m = fmaxf(m, redm[ww][h]);
        M[h] = m;
    }

    // ---- exp + block sum ----
    float ls[4] = {0.f,0.f,0.f,0.f};
    #pragma unroll
    for (int i=0;i<4;++i) {
        #pragma unroll
        for (int h=0;h<4;++h) {
            const float e = __expf(s[h][i] - M[h]);
            s[h][i] = e;
            ls[h] += e;
        }
    }
    #pragma unroll
    for (int off=1; off<64; off<<=1) {
        #pragma unroll
        for (int h=0;h<4;++h) ls[h] += __shfl_xor(ls[h], off, 64);
    }
    if (lane==0) {
        #pragma unroll
        for (int h=0;h<4;++h) reds[w][h] = ls[h];
    }
    __syncthreads();
    float inv[4];
    #pragma unroll
    for (int h=0;h<4;++h) {
        float sm = reds[0][h];
        #pragma unroll
        for (int ww=1;ww<16;++ww) sm += reds[ww][h];
        inv[h] = 1.f / sm;
    }

    // ---- write normalized probs (bf16 packed) ----
    #pragma unroll
    for (int i=0;i<4;++i) {
        const int p = i*1024 + t;
        if (p < PL) {
            const u32 plo = (u32)f2bf(s[0][i]*inv[0]) | ((u32)f2bf(s[1][i]*inv[1]) << 16);
            const u32 phi = (u32)f2bf(s[2][i]*inv[2]) | ((u32)f2bf(s[3][i]*inv[3]) << 16);
            probsP[p] = make_uint2(plo, phi);
        }
    }
    __syncthreads();

    // ---- Phase PV ----
    const float* __restrict__ Vb  = Vc + mat*(size_t)SW*128;
    const float* __restrict__ vnr = vn + mat*128;
    const int chunk = PL >> 4;
    const int p0 = w*chunk, p1 = p0 + chunk;
    float a0[4] = {0.f,0.f,0.f,0.f}, a1[4] = {0.f,0.f,0.f,0.f};
    #pragma unroll 8
    for (int p=p0; p<p1; ++p) {
        const float* row = (p==cur) ? vnr : (Vb + (size_t)p*128);
        const float2 vv = *reinterpret_cast<const float2*>(row + 2*lane);
        const uint2 pp = probsP[p];
        const float pr0 = lo2f(pp.x), pr1 = hi2f(pp.x);
        const float pr2 = lo2f(pp.y), pr3 = hi2f(pp.y);
        a0[0]=fmaf(pr0,vv.x,a0[0]); a1[0]=fmaf(pr0,vv.y,a1[0]);
        a0[1]=fmaf(pr1,vv.x,a0[1]); a1[1]=fmaf(pr1,vv.y,a1[1]);
        a0[2]=fmaf(pr2,vv.x,a0[2]); a1[2]=fmaf(pr2,vv.y,a1[2]);
        a0[3]=fmaf(pr3,vv.x,a0[3]); a1[3]=fmaf(pr3,vv.y,a1[3]);
    }
    #pragma unroll
    for (int h=0;h<4;++h)
        *reinterpret_cast<float2*>(&obuf[w][h][2*lane]) = make_float2(a0[h], a1[h]);
    __syncthreads();

    // ---- cross-wave reduce + TRANSPOSED writeout (for wo GEMM) ----
    if (t < 512) {
        const int h = t >> 7;
        const int d = t & 127;
        float sum = obuf[0][h][d];
        #pragma unroll
        for (int ww=1;ww<16;++ww) sum += obuf[ww][h][d];
        const int col = (kv*4 + h)*128 + d;
        aout_t[(size_t)col*32 + b] = sum;
    }
}

// ---------------- K5: reduce wo partials -> f32 output ----------------
__global__ __launch_bounds__(256) void wo_finish(
    const float* __restrict__ P, float* __restrict__ out, int splits)
{
    const int col = blockIdx.x*256 + threadIdx.x;
    const int b = blockIdx.y;
    float v = 0.f;
    for (int s=0;s<splits;++s) v += P[(size_t)(s*32+b)*4096 + col];
    out[(size_t)b*4096 + col] = v;
}

extern "C" void kernel_launch(void* const* d_in, const int* in_sizes, int n_in,
                              void* d_out, int out_size, void* d_ws, size_t ws_size,
                              hipStream_t stream)
{
    const float* x    = (const float*)d_in[0];
    const float* wqkv = (const float*)d_in[1];
    const float* wo   = (const float*)d_in[2];
    const float* cK   = (const float*)d_in[3];
    const float* cV   = (const float*)d_in[4];
    const float* cosc = (const float*)d_in[5];
    const float* sinc = (const float*)d_in[6];
    const float* mask = (const float*)d_in[7];
    const int* sp   = (const int*)d_in[8];
    const int* cp   = (const int*)d_in[9];

    const int PL = in_sizes[7] / (32*32);          // padded_len (4032)
    const int SW = in_sizes[3] / (32*8*128);       // cache rows (4096)

    char* ws = (char*)d_ws;
    float* xt    = (float*)(ws);                         // 512 KB
    float* qws   = (float*)(ws + 524288);                // 512 KB
    float* aout_t= (float*)(ws + 2*524288);              // 512 KB
    float* kn    = (float*)(ws + 3*524288);              // 128 KB
    float* vn    = (float*)(ws + 3*524288 + 131072);     // 128 KB
    float* Pbuf  = (float*)(ws + 3*524288 + 2*131072);   // split-K partials

    int splits = 64;
    {
        const size_t fixed = 3ull*524288 + 2ull*131072;
        while (splits > 4 && fixed + (size_t)splits*32*6144*4 > ws_size) splits >>= 1;
    }
    const int dps = 4096 / splits;

    transpose_x<<<64, 256, 0, stream>>>(x, xt);
    gemm_splitk_t<<<dim3(12, splits), 256, 0, stream>>>(xt, (const float2*)wqkv, Pbuf, 4096, 6144, dps);
    qkv_finish<<<dim3(24, 32), 256, 0, stream>>>(Pbuf, cosc, sinc, sp, qws, kn, vn, splits);

    attn_kernel<<<256, 1024, 0, stream>>>(qws, cK, cV, kn, vn, mask, cp, aout_t, PL, SW);

    gemm_splitk_t<<<dim3(8, splits), 256, 0, stream>>>(aout_t, (const float2*)wo, Pbuf, 4096, 4096, dps);
    wo_finish<<<dim3(16, 32), 256, 0, stream>>>(Pbuf, (float*)d_out, splits);
}

// Round 9
// 304.960 us; speedup vs baseline: 2.1668x; 1.1107x over previous
//
#include <hip/hip_runtime.h>
#include <hip/hip_bf16.h>

typedef unsigned int u32;
typedef unsigned short u16;

__device__ __forceinline__ u16 f2bf(float f){ u32 x; __builtin_memcpy(&x,&f,4); u32 r=(x+0x7fffu+((x>>16)&1u))>>16; return (u16)r; }
__device__ __forceinline__ float lo2f(u32 u){ u32 x=u<<16; float f; __builtin_memcpy(&f,&x,4); return f; }
__device__ __forceinline__ float hi2f(u32 u){ u32 x=u&0xffff0000u; float f; __builtin_memcpy(&f,&x,4); return f; }

// ---------------- K0: transpose x (32 x 4096) -> xt (4096 x 32) ----------------
__global__ __launch_bounds__(256) void transpose_x(
    const float* __restrict__ x, float* __restrict__ xt)
{
    __shared__ float ld[32][65];
    const int t = threadIdx.x;
    const int g = blockIdx.x;
    #pragma unroll
    for (int i=0;i<8;++i) {
        const int e = i*256 + t;
        const int b = e >> 6, dd = e & 63;
        ld[b][dd] = x[(size_t)b*4096 + g*64 + dd];
    }
    __syncthreads();
    #pragma unroll
    for (int i=0;i<8;++i) {
        const int e = i*256 + t;
        const int dd = e >> 5, b = e & 31;
        xt[(size_t)(g*64 + dd)*32 + b] = ld[b][dd];
    }
}

// ---------------- K1/K3: split-K GEMM with transposed A: (K x 32) ----------------
__global__ __launch_bounds__(256) void gemm_splitk_t(
    const float* __restrict__ At, const float2* __restrict__ W2,
    float* __restrict__ P, int K, int N, int dps)
{
    const int j2 = blockIdx.x*256 + threadIdx.x;
    const int s = blockIdx.y;
    float acc0[32], acc1[32];
    #pragma unroll
    for (int b=0;b<32;++b){ acc0[b]=0.f; acc1[b]=0.f; }
    const int d0 = s*dps, d1 = d0 + dps;
    const int halfN = N >> 1;
    #pragma unroll 2
    for (int d=d0; d<d1; ++d) {
        const float2 wv = W2[(size_t)d*halfN + j2];
        const float* __restrict__ Ad = At + d*32;   // contiguous 128B, wave-uniform -> s_load
        #pragma unroll
        for (int b=0;b<32;++b) {
            const float av = Ad[b];
            acc0[b] = fmaf(av, wv.x, acc0[b]);
            acc1[b] = fmaf(av, wv.y, acc1[b]);
        }
    }
    float* Pp = P + (size_t)(s*32)*N + 2*j2;
    #pragma unroll
    for (int b=0;b<32;++b)
        *reinterpret_cast<float2*>(Pp + (size_t)b*N) = make_float2(acc0[b], acc1[b]);
}

// ---------------- K2: reduce partials + RoPE + pack q/k/v (partner via LDS) ----------------
__global__ __launch_bounds__(256) void qkv_finish(
    const float* __restrict__ P, const float* __restrict__ cosc,
    const float* __restrict__ sinc, const int* __restrict__ spp,
    float* __restrict__ qws, float* __restrict__ kn, float* __restrict__ vn,
    int splits)
{
    __shared__ float sh[256];
    const int t = threadIdx.x;
    const int col = blockIdx.x*256 + t;
    const int b = blockIdx.y;
    float v = 0.f;
    for (int s=0;s<splits;++s) v += P[(size_t)(s*32+b)*6144 + col];
    sh[t] = v;
    __syncthreads();
    if (col < 5120) {
        const int d = col & 127;
        const int pt = (t & ~127) | ((d<64)? d+64 : d-64);
        const float pv = sh[pt];
        const int spos = *spp;
        const float c  = cosc[spos*128 + d];
        const float sn = sinc[spos*128 + d];
        const float rot = (d<64)? -pv : pv;
        const float val = fmaf(v, c, rot*sn);
        if (col < 4096) qws[(size_t)b*4096 + col] = val;
        else            kn[(size_t)b*1024 + (col-4096)] = val;
    } else {
        vn[(size_t)b*1024 + (col-5120)] = v;
    }
}

// ---------------- K4: fused attention, 16 waves/block; coalesced QK^T ----------------
__global__ __launch_bounds__(1024, 4) void attn_kernel(
    const float* __restrict__ qws, const float* __restrict__ Kc,
    const float* __restrict__ Vc, const float* __restrict__ kn,
    const float* __restrict__ vn, const float* __restrict__ mask,
    const int* __restrict__ curp, float* __restrict__ aout_t,
    const int PL, const int SW)
{
    __shared__ float scoresS[4*4100];     // 64.1 KB raw scores [h][p]
    __shared__ uint2 probsP[4096];        // 32 KB: 4 bf16 probs per position
    __shared__ float obuf[16][4][128];    // 32 KB
    __shared__ float redm[16][4];
    __shared__ float reds[16][4];

    const int t = threadIdx.x;
    const int lane = t & 63;
    const int w = t >> 6;
    const int b  = blockIdx.x >> 3;
    const int kv = blockIdx.x & 7;
    const int cur = *curp;

    const size_t mat = (size_t)(b*8+kv);
    const float* __restrict__ Kb  = Kc + mat*(size_t)SW*128;
    const float* __restrict__ knr = kn + mat*128;
    const float* __restrict__ qbase = qws + (size_t)(b*32 + kv*4)*128;

    // ---- Phase A: cooperative QK^T. 16-lane group per row; lane l covers d=[8l,8l+8). ----
    const int l   = lane & 15;
    const int grp = lane >> 4;
    float qv[4][8];
    #pragma unroll
    for (int h=0;h<4;++h)
        #pragma unroll
        for (int j=0;j<8;++j)
            qv[h][j] = qbase[h*128 + l*8 + j];

    const int rpw = PL >> 4;           // rows per wave (252); PL % 64 == 0
    const int rb0 = w * rpw;
    for (int g=0; g<rpw; g+=4) {
        const int r = rb0 + g + grp;
        const float* __restrict__ row = (r==cur) ? knr : (Kb + (size_t)r*128);
        const float4 ka = *reinterpret_cast<const float4*>(row + l*8);
        const float4 kb4 = *reinterpret_cast<const float4*>(row + l*8 + 4);
        float kf[8];
        kf[0]=ka.x; kf[1]=ka.y; kf[2]=ka.z; kf[3]=ka.w;
        kf[4]=kb4.x; kf[5]=kb4.y; kf[6]=kb4.z; kf[7]=kb4.w;
        float sc0=0.f, sc1=0.f, sc2=0.f, sc3=0.f;
        #pragma unroll
        for (int j=0;j<8;++j) {
            sc0 = fmaf(qv[0][j], kf[j], sc0);
            sc1 = fmaf(qv[1][j], kf[j], sc1);
            sc2 = fmaf(qv[2][j], kf[j], sc2);
            sc3 = fmaf(qv[3][j], kf[j], sc3);
        }
        #pragma unroll
        for (int off=8; off; off>>=1) {
            sc0 += __shfl_xor(sc0, off, 16);
            sc1 += __shfl_xor(sc1, off, 16);
            sc2 += __shfl_xor(sc2, off, 16);
            sc3 += __shfl_xor(sc3, off, 16);
        }
        if (l < 4) {
            const float v = (l==0)?sc0:(l==1)?sc1:(l==2)?sc2:sc3;
            scoresS[l*4100 + r] = v;
        }
    }
    __syncthreads();

    // ---- Phase B: scale + mask + softmax (old coalesced p-mapping) ----
    const float scale = 0.08838834764831845f; // 1/sqrt(128)
    const size_t mbase = ((size_t)b*32 + (size_t)kv*4)*(size_t)PL;
    float s[4][4];
    #pragma unroll
    for (int i=0;i<4;++i) {
        const int p = i*1024 + t;
        if (p < PL) {
            #pragma unroll
            for (int h=0;h<4;++h) {
                const float mv = mask[mbase + (size_t)h*PL + p];
                s[h][i] = fmaf(scoresS[h*4100 + p], scale, mv);
            }
        } else {
            #pragma unroll
            for (int h=0;h<4;++h) s[h][i] = -3.0e38f;
        }
    }

    float lm[4];
    #pragma unroll
    for (int h=0;h<4;++h)
        lm[h] = fmaxf(fmaxf(s[h][0],s[h][1]), fmaxf(s[h][2],s[h][3]));
    #pragma unroll
    for (int off=1; off<64; off<<=1) {
        #pragma unroll
        for (int h=0;h<4;++h) lm[h] = fmaxf(lm[h], __shfl_xor(lm[h], off, 64));
    }
    if (lane==0) {
        #pragma unroll
        for (int h=0;h<4;++h) redm[w][h] = lm[h];
    }
    __syncthreads();
    float M[4];
    #pragma unroll
    for (int h=0;h<4;++h) {
        float m = redm[0][h];
        #pragma unroll
        for (int ww=1;ww<16;++ww) m = fmaxf(m, redm[ww][h]);
        M[h] = m;
    }

    float ls[4] = {0.f,0.f,0.f,0.f};
    #pragma unroll
    for (int i=0;i<4;++i) {
        #pragma unroll
        for (int h=0;h<4;++h) {
            const float e = __expf(s[h][i] - M[h]);
            s[h][i] = e;
            ls[h] += e;
        }
    }
    #pragma unroll
    for (int off=1; off<64; off<<=1) {
        #pragma unroll
        for (int h=0;h<4;++h) ls[h] += __shfl_xor(ls[h], off, 64);
    }
    if (lane==0) {
        #pragma unroll
        for (int h=0;h<4;++h) reds[w][h] = ls[h];
    }
    __syncthreads();
    float inv[4];
    #pragma unroll
    for (int h=0;h<4;++h) {
        float sm = reds[0][h];
        #pragma unroll
        for (int ww=1;ww<16;++ww) sm += reds[ww][h];
        inv[h] = 1.f / sm;
    }

    #pragma unroll
    for (int i=0;i<4;++i) {
        const int p = i*1024 + t;
        if (p < PL) {
            const u32 plo = (u32)f2bf(s[0][i]*inv[0]) | ((u32)f2bf(s[1][i]*inv[1]) << 16);
            const u32 phi = (u32)f2bf(s[2][i]*inv[2]) | ((u32)f2bf(s[3][i]*inv[3]) << 16);
            probsP[p] = make_uint2(plo, phi);
        }
    }
    __syncthreads();

    // ---- Phase PV: wave w covers its row chunk; lane covers d=2*lane,2*lane+1 (coalesced) ----
    const float* __restrict__ Vb  = Vc + mat*(size_t)SW*128;
    const float* __restrict__ vnr = vn + mat*128;
    const int chunk = PL >> 4;
    const int p0 = w*chunk, p1 = p0 + chunk;
    float a0[4] = {0.f,0.f,0.f,0.f}, a1[4] = {0.f,0.f,0.f,0.f};
    #pragma unroll 8
    for (int p=p0; p<p1; ++p) {
        const float* row = (p==cur) ? vnr : (Vb + (size_t)p*128);
        const float2 vv = *reinterpret_cast<const float2*>(row + 2*lane);
        const uint2 pp = probsP[p];
        const float pr0 = lo2f(pp.x), pr1 = hi2f(pp.x);
        const float pr2 = lo2f(pp.y), pr3 = hi2f(pp.y);
        a0[0]=fmaf(pr0,vv.x,a0[0]); a1[0]=fmaf(pr0,vv.y,a1[0]);
        a0[1]=fmaf(pr1,vv.x,a0[1]); a1[1]=fmaf(pr1,vv.y,a1[1]);
        a0[2]=fmaf(pr2,vv.x,a0[2]); a1[2]=fmaf(pr2,vv.y,a1[2]);
        a0[3]=fmaf(pr3,vv.x,a0[3]); a1[3]=fmaf(pr3,vv.y,a1[3]);
    }
    #pragma unroll
    for (int h=0;h<4;++h)
        *reinterpret_cast<float2*>(&obuf[w][h][2*lane]) = make_float2(a0[h], a1[h]);
    __syncthreads();

    // ---- cross-wave reduce + TRANSPOSED writeout (for wo GEMM) ----
    if (t < 512) {
        const int h = t >> 7;
        const int d = t & 127;
        float sum = obuf[0][h][d];
        #pragma unroll
        for (int ww=1;ww<16;++ww) sum += obuf[ww][h][d];
        const int col = (kv*4 + h)*128 + d;
        aout_t[(size_t)col*32 + b] = sum;
    }
}

// ---------------- K5: reduce wo partials -> f32 output ----------------
__global__ __launch_bounds__(256) void wo_finish(
    const float* __restrict__ P, float* __restrict__ out, int splits)
{
    const int col = blockIdx.x*256 + threadIdx.x;
    const int b = blockIdx.y;
    float v = 0.f;
    for (int s=0;s<splits;++s) v += P[(size_t)(s*32+b)*4096 + col];
    out[(size_t)b*4096 + col] = v;
}

extern "C" void kernel_launch(void* const* d_in, const int* in_sizes, int n_in,
                              void* d_out, int out_size, void* d_ws, size_t ws_size,
                              hipStream_t stream)
{
    const float* x    = (const float*)d_in[0];
    const float* wqkv = (const float*)d_in[1];
    const float* wo   = (const float*)d_in[2];
    const float* cK   = (const float*)d_in[3];
    const float* cV   = (const float*)d_in[4];
    const float* cosc = (const float*)d_in[5];
    const float* sinc = (const float*)d_in[6];
    const float* mask = (const float*)d_in[7];
    const int* sp   = (const int*)d_in[8];
    const int* cp   = (const int*)d_in[9];

    const int PL = in_sizes[7] / (32*32);          // padded_len (4032)
    const int SW = in_sizes[3] / (32*8*128);       // cache rows (4096)

    char* ws = (char*)d_ws;
    float* xt    = (float*)(ws);                         // 512 KB
    float* qws   = (float*)(ws + 524288);                // 512 KB
    float* aout_t= (float*)(ws + 2*524288);              // 512 KB
    float* kn    = (float*)(ws + 3*524288);              // 128 KB
    float* vn    = (float*)(ws + 3*524288 + 131072);     // 128 KB
    float* Pbuf  = (float*)(ws + 3*524288 + 2*131072);   // split-K partials

    int splits = 64;
    {
        const size_t fixed = 3ull*524288 + 2ull*131072;
        while (splits > 4 && fixed + (size_t)splits*32*6144*4 > ws_size) splits >>= 1;
    }
    const int dps = 4096 / splits;

    transpose_x<<<64, 256, 0, stream>>>(x, xt);
    gemm_splitk_t<<<dim3(12, splits), 256, 0, stream>>>(xt, (const float2*)wqkv, Pbuf, 4096, 6144, dps);
    qkv_finish<<<dim3(24, 32), 256, 0, stream>>>(Pbuf, cosc, sinc, sp, qws, kn, vn, splits);

    attn_kernel<<<256, 1024, 0, stream>>>(qws, cK, cV, kn, vn, mask, cp, aout_t, PL, SW);

    gemm_splitk_t<<<dim3(8, splits), 256, 0, stream>>>(aout_t, (const float2*)wo, Pbuf, 4096, 4096, dps);
    wo_finish<<<dim3(16, 32), 256, 0, stream>>>(Pbuf, (float*)d_out, splits);
}